// Round 1
// baseline (298.542 us; speedup 1.0000x reference)
//
#include <hip/hip_runtime.h>
#include <hip/hip_bf16.h>
#include <math.h>

// Problem constants
#define IN_DIM   384
#define GNN_DIM  256
#define HEADS    4
#define DH       64
#define N_PATCH  8192
#define N_TILES  128
#define N_EDGES  1024
#define N_TOT    (N_PATCH + N_TILES)   // 8320
#define NTB      (N_TOT / 8)           // 1040 bytes per HTb row
#define NEB      (N_EDGES / 8)         // 128 bytes per HNb row
#define CCAP     800                   // phaseC member capacity (mean ~500, +13 sigma)
#define ECAP     1032                  // phaseE edge capacity (max 1024 + pad)

typedef short  bf16x8 __attribute__((ext_vector_type(8)));
typedef float  f32x4  __attribute__((ext_vector_type(4)));

// ---------------------------------------------------------------------------
__device__ __forceinline__ float waveReduce(float v) {
    #pragma unroll
    for (int o = 32; o > 0; o >>= 1) v += __shfl_down(v, o, 64);
    return v; // valid in lane 0 of each 64-wide wave
}

__device__ __forceinline__ unsigned packbf2(float a, float b) {
    __hip_bfloat16 b0 = __float2bfloat16(a), b1 = __float2bfloat16(b);
    unsigned short u0, u1;
    __builtin_memcpy(&u0, &b0, 2);
    __builtin_memcpy(&u1, &b1, 2);
    return (unsigned)u0 | ((unsigned)u1 << 16);
}

// ---------------------------------------------------------------------------
// Fused prep kernel (grid-partitioned): unchanged from previous best.
// ---------------------------------------------------------------------------
__global__ __launch_bounds__(256) void prep1(
    const float* __restrict__ H,
    unsigned char* __restrict__ HTb, unsigned char* __restrict__ HNb,
    const float* __restrict__ W0, __hip_bfloat16* __restrict__ Wt0,
    const float* __restrict__ W1, __hip_bfloat16* __restrict__ Wt1,
    const float* __restrict__ x, const float* __restrict__ ro,
    __hip_bfloat16* __restrict__ Xb,
    const int* __restrict__ ro_ids, int* __restrict__ outrow)
{
    __shared__ unsigned char tb[32][33];
    __shared__ float tf[32][33];
    int b = blockIdx.x, tid = threadIdx.x;
    int tx = tid & 31, ty = tid >> 5;          // ty in 0..7

    if (b < 8320) {
        int n0 = (b % 260) * 32;
        int e0 = (b / 260) * 32;
        #pragma unroll
        for (int r = 0; r < 4; ++r) {
            int row = ty + r * 8;
            tb[row][tx] = (H[(size_t)(n0 + row) * N_EDGES + e0 + tx] > 0.f) ? 1 : 0;
        }
        __syncthreads();
        if (tid < 128) {            // HTb: 32 edges x 4 node-bytes
            int er = tid >> 2, g = tid & 3;
            unsigned v = 0;
            #pragma unroll
            for (int i = 0; i < 8; ++i) v |= (unsigned)tb[g * 8 + i][er] << i;
            HTb[(size_t)(e0 + er) * NTB + (n0 >> 3) + g] = (unsigned char)v;
        } else {                    // HNb: 32 nodes x 4 edge-bytes
            int id = tid - 128;
            int nr = id >> 2, g = id & 3;
            unsigned v = 0;
            #pragma unroll
            for (int i = 0; i < 8; ++i) v |= (unsigned)tb[nr][g * 8 + i] << i;
            HNb[(size_t)(n0 + nr) * NEB + (e0 >> 3) + g] = (unsigned char)v;
        }
    } else if (b < 8480) {
        const float* W; __hip_bfloat16* Wt; int K, k0, n0;
        if (b < 8416) {
            int i = b - 8320; W = W0; Wt = Wt0; K = IN_DIM;
            k0 = (i % 12) * 32; n0 = (i / 12) * 32;
        } else {
            int i = b - 8416; W = W1; Wt = Wt1; K = GNN_DIM;
            k0 = (i % 8) * 32; n0 = (i / 8) * 32;
        }
        #pragma unroll
        for (int r = 0; r < 4; ++r)
            tf[ty + r * 8][tx] = W[(size_t)(k0 + ty + r * 8) * GNN_DIM + n0 + tx];
        __syncthreads();
        #pragma unroll
        for (int r = 0; r < 4; ++r)
            Wt[(size_t)(n0 + ty + r * 8) * K + k0 + tx] =
                __float2bfloat16(tf[tx][ty + r * 8]);
    } else if (b < 9000) {
        int nb = (b - 8480) * 16;
        for (int r = 0; r < 16; ++r) {
            int n = nb + r;
            for (int k = tid; k < IN_DIM; k += 256) {
                float v = (n < N_PATCH) ? x[(size_t)n * IN_DIM + k] : ro[k];
                Xb[(size_t)n * IN_DIM + k] = __float2bfloat16(v);
            }
        }
    } else {
        if (tid < N_TILES) {
            int r = ro_ids[tid] - N_PATCH;
            if (r >= 0 && r < N_TILES) outrow[r] = tid;
        }
    }
}

// ---------------------------------------------------------------------------
// Phase A (MFMA): h = Xb @ Wt^T + nemb[node_type]; fused s_src/s_dst/expL.
// Unchanged from previous best.
// ---------------------------------------------------------------------------
__global__ __launch_bounds__(256) void phaseA_mfma(
    const __hip_bfloat16* __restrict__ Xb,  // [N_TOT, K] bf16
    const __hip_bfloat16* __restrict__ Wt,  // [256, K] bf16
    int K, int KP,                          // KP = K+8 (LDS row stride)
    const float* __restrict__ nemb,
    const int* __restrict__ node_type,
    const float* __restrict__ asrc, const float* __restrict__ adst,
    const float* __restrict__ ebias,
    float* __restrict__ hP, __hip_bfloat16* __restrict__ hPb,
    float* __restrict__ expL, float* __restrict__ sdst)
{
    __shared__ char smem[16 * 260 * 4];     // 16.6 KB, union of xs / cs
    unsigned short* xs = (unsigned short*)smem;  // [16][KP] bf16 bits
    float* cs = (float*)smem;                    // [16][260] f32

    int tid = threadIdx.x;
    int n0 = blockIdx.x * 16;

    {
        int lr = tid >> 4, lc = tid & 15;
        for (int c = lc * 8; c < K; c += 128)
            *(uint4*)&xs[lr * KP + c] = *(const uint4*)&Xb[(size_t)(n0 + lr) * K + c];
    }
    __syncthreads();

    int wave = tid >> 6, lane = tid & 63;
    int lr16 = lane & 15, quad = lane >> 4;

    f32x4 acc[4];
    #pragma unroll
    for (int ct = 0; ct < 4; ++ct)
        acc[ct] = (f32x4){0.f, 0.f, 0.f, 0.f};

    for (int kc = 0; kc < K; kc += 32) {
        bf16x8 a = *(const bf16x8*)&xs[lr16 * KP + kc + quad * 8];
        #pragma unroll
        for (int ct = 0; ct < 4; ++ct) {
            int col = wave * 64 + ct * 16 + lr16;
            bf16x8 b = *(const bf16x8*)&Wt[(size_t)col * K + kc + quad * 8];
            acc[ct] = __builtin_amdgcn_mfma_f32_16x16x32_bf16(a, b, acc[ct], 0, 0, 0);
        }
    }
    __syncthreads();   // xs dead; reuse as cs

    #pragma unroll
    for (int ct = 0; ct < 4; ++ct)
        #pragma unroll
        for (int g = 0; g < 4; ++g)
            cs[(quad * 4 + g) * 260 + wave * 64 + ct * 16 + lr16] = acc[ct][g];
    __syncthreads();

    int j = tid, h = j >> 6, l2 = j & 63;
    float as = asrc[h * DH + l2];
    float ad = adst[h * DH + l2];
    float eb0 = ebias[0 * HEADS + h], eb1 = ebias[1 * HEADS + h], eb2 = ebias[2 * HEADS + h];
    for (int r = 0; r < 16; ++r) {
        int n = n0 + r;
        float hv = cs[r * 260 + j] + nemb[node_type[n] * GNN_DIM + j];
        hP[(size_t)n * GNN_DIM + j] = hv;
        hPb[(size_t)n * GNN_DIM + j] = __float2bfloat16(hv);
        float ss = waveReduce(hv * as);
        float sd = waveReduce(hv * ad);
        if (l2 == 0) {
            sdst[n * HEADS + h] = sd;
            float l0 = ss + eb0; l0 = l0 > 0.f ? l0 : 0.2f * l0;
            float l1 = ss + eb1; l1 = l1 > 0.f ? l1 : 0.2f * l1;
            float lc2 = ss + eb2; lc2 = lc2 > 0.f ? lc2 : 0.2f * lc2;
            expL[n * 12 + 0 * HEADS + h] = __expf(l0);
            expL[n * 12 + 1 * HEADS + h] = __expf(l1);
            expL[n * 12 + 2 * HEADS + h] = __expf(lc2);
        }
    }
}

// ---------------------------------------------------------------------------
// Phase C FUSED: one block per edge (512 threads). Popcount+scan compaction
// (sorted, no LDS atomics), full-edge accumulation (no macc round-trip),
// normalize + bf16 mb + sedg in the same kernel (phaseC_red eliminated).
// 4-way member split across thread quads, 2 cols/thread uint loads.
// ---------------------------------------------------------------------------
__global__ __launch_bounds__(512) void phaseC_fused(
    const unsigned char* __restrict__ HTb,   // [E, N_TOT/8] bits
    const int* __restrict__ edge_type,
    const float* __restrict__ expL,          // [N,3,4]
    const __hip_bfloat16* __restrict__ hPb,  // [N,256] bf16
    const float* __restrict__ aedg,          // [4,64]
    __hip_bfloat16* __restrict__ mb, float* __restrict__ sedg)
{
    int e = blockIdx.x, j = threadIdx.x;
    int lane = j & 63, wv = j >> 6;
    __shared__ __align__(16) int   noff[CCAP];   // sorted member byte-offsets (n<<9)
    __shared__ __align__(16) float wh[4][CCAP];  // per-head weights
    __shared__ float Zs[4];
    __shared__ float comb[3][128][2];
    __shared__ int   wtot[8];
    __shared__ int   tailc[4];

    const unsigned* Hu = (const unsigned*)(HTb + (size_t)e * NTB);
    int te = edge_type[e];

    // --- compaction: popcount + wave prefix scan (sorted, atomic-free) ---
    unsigned u = (j < 256) ? Hu[j] : 0u;   // thread t owns nodes [32t,32t+32)
    int cnt = __popc(u);
    int s = cnt;
    #pragma unroll
    for (int o = 1; o < 64; o <<= 1) {
        int v = __shfl_up(s, o, 64);
        if (lane >= o) s += v;
    }
    if (lane == 63) wtot[wv] = s;
    if (j < 4) tailc[j] = __popc(Hu[256 + j]);   // tail nodes 8192..8319
    __syncthreads();

    int base = 0, mainTot = 0;
    #pragma unroll
    for (int w = 0; w < 8; ++w) {
        int t = wtot[w];
        if (w < wv) base += t;
        mainTot += t;
    }
    int cfull = mainTot + tailc[0] + tailc[1] + tailc[2] + tailc[3];
    int c = min(cfull, CCAP - 16);   // 13-sigma headroom; never trips in practice
    {
        int off = base + s - cnt;    // exclusive offset
        int nb = j << 5;
        while (u) {
            int i = __ffs(u) - 1; u &= u - 1;
            if (off < CCAP) noff[off] = (nb + i) << 9;
            ++off;
        }
        if (j < 4) {                 // append tail, still sorted
            int tb = mainTot;
            for (int k = 0; k < j; ++k) tb += tailc[k];
            unsigned ut = Hu[256 + j];
            int nb2 = (256 + j) << 5;
            while (ut) {
                int i = __ffs(ut) - 1; ut &= ut - 1;
                if (tb < CCAP) noff[tb] = (nb2 + i) << 9;
                ++tb;
            }
        }
    }
    __syncthreads();

    int cP = (c + 15) & ~15;
    for (int i = j; i < c; i += 512) {
        int n = noff[i] >> 9;
        float4 w = *(const float4*)&expL[n * 12 + te * 4];
        wh[0][i] = w.x; wh[1][i] = w.y; wh[2][i] = w.z; wh[3][i] = w.w;
    }
    if (j < 16) {
        int i = c + j;
        if (i < cP) { noff[i] = 0; wh[0][i] = wh[1][i] = wh[2][i] = wh[3][i] = 0.f; }
    }
    __syncthreads();

    if (j < 256) {                   // per-head Z (wave w <-> head w)
        float p = 0.f;
        for (int i = lane; i < c; i += 64) p += wh[wv][i];
        p = waveReduce(p);
        if (lane == 0) Zs[wv] = p;
    }
    __syncthreads();

    // --- gather: quad q handles members i = q*4 + 16k (sorted -> L2 stream) ---
    int q = j >> 7, p = j & 127, h2 = p >> 5;
    const char* hb = (const char*)hPb;
    int coff = p << 2;
    float al0 = 0.f, ah0 = 0.f, al1 = 0.f, ah1 = 0.f;
    for (int i = q * 4; i < cP; i += 16) {
        int4   n4 = *(const int4*)&noff[i];
        float4 w4 = *(const float4*)&wh[h2][i];
        unsigned u0 = *(const unsigned*)(hb + n4.x + coff);
        unsigned u1 = *(const unsigned*)(hb + n4.y + coff);
        unsigned u2 = *(const unsigned*)(hb + n4.z + coff);
        unsigned u3 = *(const unsigned*)(hb + n4.w + coff);
        al0 += w4.x * __uint_as_float(u0 << 16);
        ah0 += w4.x * __uint_as_float(u0 & 0xffff0000u);
        al1 += w4.y * __uint_as_float(u1 << 16);
        ah1 += w4.y * __uint_as_float(u1 & 0xffff0000u);
        al0 += w4.z * __uint_as_float(u2 << 16);
        ah0 += w4.z * __uint_as_float(u2 & 0xffff0000u);
        al1 += w4.w * __uint_as_float(u3 << 16);
        ah1 += w4.w * __uint_as_float(u3 & 0xffff0000u);
    }
    float s0 = al0 + al1, s1 = ah0 + ah1;
    if (q > 0) { comb[q - 1][p][0] = s0; comb[q - 1][p][1] = s1; }
    __syncthreads();
    if (q == 0) {
        s0 += comb[0][p][0] + comb[1][p][0] + comb[2][p][0];
        s1 += comb[0][p][1] + comb[1][p][1] + comb[2][p][1];
        float Zi = 1.f / Zs[h2];
        float mv0 = s0 * Zi, mv1 = s1 * Zi;
        ((unsigned*)mb)[e * 128 + p] = packbf2(mv0, mv1);
        int d0 = (p & 31) << 1;
        float se = mv0 * aedg[h2 * DH + d0] + mv1 * aedg[h2 * DH + d0 + 1];
        #pragma unroll
        for (int o = 16; o > 0; o >>= 1) se += __shfl_down(se, o, 32);
        if ((p & 31) == 0) sedg[e * HEADS + h2] = se;
    }
}

// ---------------------------------------------------------------------------
// Phase E (layer 0): uint (4B) gather loads, 2 cols/thread, member-parity
// split across thread halves, combined via LDS. Writes bf16 hOutb only.
// ---------------------------------------------------------------------------
__global__ __launch_bounds__(256) void phaseE(
    const unsigned char* __restrict__ HNb,   // [N, E/8] bits
    const float* __restrict__ sdstArr,       // [N,4]
    const float* __restrict__ sedg,          // [E,4]
    const __hip_bfloat16* __restrict__ mb,   // [E,256] bf16
    const float* __restrict__ hP,            // [N,256] residual
    __hip_bfloat16* __restrict__ hOutb)
{
    int n = blockIdx.x, j = threadIdx.x;
    int lane = j & 63, wv = j >> 6;
    __shared__ int cnt;
    __shared__ __align__(16) int   eidx[ECAP];   // edge byte-offsets (e<<9)
    __shared__ __align__(16) float wh[4][ECAP];
    __shared__ float Zs[4];
    __shared__ float comb[128][2];
    __shared__ float sdv[4];
    if (j < 4) sdv[j] = sdstArr[n * HEADS + j];
    if (j == 0) cnt = 0;
    __syncthreads();
    if (j < 32) {
        unsigned b = ((const unsigned*)(HNb + (size_t)n * NEB))[j];
        int eb = j << 5;
        while (b) {
            int i = __ffs(b) - 1; b &= b - 1;
            int p = atomicAdd(&cnt, 1);
            eidx[p] = (eb + i) << 9;
        }
    }
    __syncthreads();
    int c = cnt;
    int cP = (c + 7) & ~7;
    for (int i = j; i < c; i += 256) {
        int e = eidx[i] >> 9;
        float4 sg = *(const float4*)&sedg[e * 4];
        float l0 = sdv[0] + sg.x; l0 = l0 > 0.f ? l0 : 0.2f * l0;
        float l1 = sdv[1] + sg.y; l1 = l1 > 0.f ? l1 : 0.2f * l1;
        float l2 = sdv[2] + sg.z; l2 = l2 > 0.f ? l2 : 0.2f * l2;
        float l3 = sdv[3] + sg.w; l3 = l3 > 0.f ? l3 : 0.2f * l3;
        wh[0][i] = __expf(l0); wh[1][i] = __expf(l1);
        wh[2][i] = __expf(l2); wh[3][i] = __expf(l3);
    }
    if (j < 8) {
        int i = c + j;
        if (i < cP) { eidx[i] = 0; wh[0][i] = wh[1][i] = wh[2][i] = wh[3][i] = 0.f; }
    }
    __syncthreads();
    {
        float p = 0.f;
        for (int i = lane; i < c; i += 64) p += wh[wv][i];
        p = waveReduce(p);
        if (lane == 0) Zs[wv] = p;
    }
    __syncthreads();

    int par = j >> 7, p = j & 127, h2 = p >> 5;
    const char* mbb = (const char*)mb;
    int coff = p << 2;
    float a0 = 0.f, b0 = 0.f, a1 = 0.f, b1 = 0.f;
    for (int i = par * 4; i < cP; i += 8) {
        int4   e4 = *(const int4*)&eidx[i];
        float4 w4 = *(const float4*)&wh[h2][i];
        unsigned u0 = *(const unsigned*)(mbb + e4.x + coff);
        unsigned u1 = *(const unsigned*)(mbb + e4.y + coff);
        unsigned u2 = *(const unsigned*)(mbb + e4.z + coff);
        unsigned u3 = *(const unsigned*)(mbb + e4.w + coff);
        a0 += w4.x * __uint_as_float(u0 << 16);
        b0 += w4.x * __uint_as_float(u0 & 0xffff0000u);
        a1 += w4.y * __uint_as_float(u1 << 16);
        b1 += w4.y * __uint_as_float(u1 & 0xffff0000u);
        a0 += w4.z * __uint_as_float(u2 << 16);
        b0 += w4.z * __uint_as_float(u2 & 0xffff0000u);
        a1 += w4.w * __uint_as_float(u3 << 16);
        b1 += w4.w * __uint_as_float(u3 & 0xffff0000u);
    }
    if (par == 1) { comb[p][0] = a0 + a1; comb[p][1] = b0 + b1; }
    __syncthreads();
    if (par == 0) {
        float o0 = a0 + a1 + comb[p][0];
        float o1 = b0 + b1 + comb[p][1];
        float Zi = 1.f / Zs[h2];
        o0 *= Zi; o1 *= Zi;
        o0 = o0 > 0.f ? o0 : expm1f(o0);   // ELU (alpha=1)
        o1 = o1 > 0.f ? o1 : expm1f(o1);
        float2 hr = *(const float2*)&hP[(size_t)n * GNN_DIM + 2 * p];
        ((unsigned*)hOutb)[n * 128 + p] = packbf2(o0 + hr.x, o1 + hr.y);
    }
}

// ---------------------------------------------------------------------------
// Phase E last (layer 1): same gather body + fused final layernorm -> d_out.
// ---------------------------------------------------------------------------
__global__ __launch_bounds__(256) void phaseE_last(
    const unsigned char* __restrict__ HNb,
    const float* __restrict__ sdstArr,
    const float* __restrict__ sedg,
    const __hip_bfloat16* __restrict__ mb,
    const float* __restrict__ hP,
    const float* __restrict__ ng, const float* __restrict__ nbeta,
    const float* __restrict__ bg, const float* __restrict__ bbeta,
    const int* __restrict__ outrow,
    float* __restrict__ out)
{
    int n = blockIdx.x, j = threadIdx.x;
    int lane = j & 63, wv = j >> 6;
    __shared__ int cnt;
    __shared__ __align__(16) int   eidx[ECAP];
    __shared__ __align__(16) float wh[4][ECAP];
    __shared__ float Zs[4];
    __shared__ float comb[128][2];
    __shared__ float sdv[4];
    __shared__ float red[4];
    if (j < 4) sdv[j] = sdstArr[n * HEADS + j];
    if (j == 0) cnt = 0;
    __syncthreads();
    if (j < 32) {
        unsigned b = ((const unsigned*)(HNb + (size_t)n * NEB))[j];
        int eb = j << 5;
        while (b) {
            int i = __ffs(b) - 1; b &= b - 1;
            int p = atomicAdd(&cnt, 1);
            eidx[p] = (eb + i) << 9;
        }
    }
    __syncthreads();
    int c = cnt;
    int cP = (c + 7) & ~7;
    for (int i = j; i < c; i += 256) {
        int e = eidx[i] >> 9;
        float4 sg = *(const float4*)&sedg[e * 4];
        float l0 = sdv[0] + sg.x; l0 = l0 > 0.f ? l0 : 0.2f * l0;
        float l1 = sdv[1] + sg.y; l1 = l1 > 0.f ? l1 : 0.2f * l1;
        float l2 = sdv[2] + sg.z; l2 = l2 > 0.f ? l2 : 0.2f * l2;
        float l3 = sdv[3] + sg.w; l3 = l3 > 0.f ? l3 : 0.2f * l3;
        wh[0][i] = __expf(l0); wh[1][i] = __expf(l1);
        wh[2][i] = __expf(l2); wh[3][i] = __expf(l3);
    }
    if (j < 8) {
        int i = c + j;
        if (i < cP) { eidx[i] = 0; wh[0][i] = wh[1][i] = wh[2][i] = wh[3][i] = 0.f; }
    }
    __syncthreads();
    {
        float p = 0.f;
        for (int i = lane; i < c; i += 64) p += wh[wv][i];
        p = waveReduce(p);
        if (lane == 0) Zs[wv] = p;
    }
    __syncthreads();

    int par = j >> 7, p = j & 127, h2 = p >> 5;
    const char* mbb = (const char*)mb;
    int coff = p << 2;
    float a0 = 0.f, b0 = 0.f, a1 = 0.f, b1 = 0.f;
    for (int i = par * 4; i < cP; i += 8) {
        int4   e4 = *(const int4*)&eidx[i];
        float4 w4 = *(const float4*)&wh[h2][i];
        unsigned u0 = *(const unsigned*)(mbb + e4.x + coff);
        unsigned u1 = *(const unsigned*)(mbb + e4.y + coff);
        unsigned u2 = *(const unsigned*)(mbb + e4.z + coff);
        unsigned u3 = *(const unsigned*)(mbb + e4.w + coff);
        a0 += w4.x * __uint_as_float(u0 << 16);
        b0 += w4.x * __uint_as_float(u0 & 0xffff0000u);
        a1 += w4.y * __uint_as_float(u1 << 16);
        b1 += w4.y * __uint_as_float(u1 & 0xffff0000u);
        a0 += w4.z * __uint_as_float(u2 << 16);
        b0 += w4.z * __uint_as_float(u2 & 0xffff0000u);
        a1 += w4.w * __uint_as_float(u3 << 16);
        b1 += w4.w * __uint_as_float(u3 & 0xffff0000u);
    }
    if (par == 1) { comb[p][0] = a0 + a1; comb[p][1] = b0 + b1; }
    __syncthreads();

    float r0 = 0.f, r1 = 0.f;
    if (par == 0) {
        float o0 = a0 + a1 + comb[p][0];
        float o1 = b0 + b1 + comb[p][1];
        float Zi = 1.f / Zs[h2];
        o0 *= Zi; o1 *= Zi;
        o0 = o0 > 0.f ? o0 : expm1f(o0);
        o1 = o1 > 0.f ? o1 : expm1f(o1);
        float2 hr = *(const float2*)&hP[(size_t)n * GNN_DIM + 2 * p];
        r0 = o0 + hr.x; r1 = o1 + hr.y;
    }

    // fused layernorm over this node's 256 columns (par==1 contributes 0)
    float sm = waveReduce(r0 + r1);
    if (lane == 0) red[wv] = sm;
    __syncthreads();
    float mean = (red[0] + red[1] + red[2] + red[3]) * (1.f / GNN_DIM);
    __syncthreads();
    float d0 = r0 - mean, d1 = r1 - mean;
    float sv = (par == 0) ? (d0 * d0 + d1 * d1) : 0.f;
    sv = waveReduce(sv);
    if (lane == 0) red[wv] = sv;
    __syncthreads();
    float var = (red[0] + red[1] + red[2] + red[3]) * (1.f / GNN_DIM);
    if (par == 0) {
        const float* g; const float* bta; size_t outOff;
        if (n < N_PATCH) { g = ng; bta = nbeta; outOff = (size_t)n * GNN_DIM; }
        else {
            int qq = outrow[n - N_PATCH];
            g = bg; bta = bbeta;
            outOff = (size_t)(N_PATCH + qq) * GNN_DIM;
        }
        float is = rsqrtf(var + 1e-5f);
        float2 gv = *(const float2*)&g[2 * p];
        float2 bv = *(const float2*)&bta[2 * p];
        float2 ov; ov.x = d0 * is * gv.x + bv.x; ov.y = d1 * is * gv.y + bv.y;
        *(float2*)&out[outOff + 2 * p] = ov;
    }
}

// ---------------------------------------------------------------------------
extern "C" void kernel_launch(void* const* d_in, const int* in_sizes, int n_in,
                              void* d_out, int out_size, void* d_ws, size_t ws_size,
                              hipStream_t stream) {
    const float* x_nodes   = (const float*)d_in[0];
    const float* readout   = (const float*)d_in[1];
    const int*   node_type = (const int*)d_in[2];
    const int*   edge_type = (const int*)d_in[3];
    const float* Hmat      = (const float*)d_in[4];
    const int*   ro_ids    = (const int*)d_in[5];
    const float* W0        = (const float*)d_in[6];
    const float* W1        = (const float*)d_in[7];
    const float* node_emb  = (const float*)d_in[8];
    const float* a_src     = (const float*)d_in[9];
    const float* a_dst     = (const float*)d_in[10];
    const float* a_edge    = (const float*)d_in[11];
    const float* edge_bias = (const float*)d_in[12];
    const float* node_g    = (const float*)d_in[13];
    const float* node_b    = (const float*)d_in[14];
    const float* bag_g     = (const float*)d_in[15];
    const float* bag_b     = (const float*)d_in[16];

    // Workspace layout (~22.7 MB; macc/Zacc eliminated by fused phaseC)
    char* ws = (char*)d_ws;
    size_t off = 0;
    unsigned char* HTb = (unsigned char*)(ws + off); off += (size_t)N_EDGES * NTB;
    unsigned char* HNb = (unsigned char*)(ws + off); off += (size_t)N_TOT * NEB;
    off = (off + 255) & ~(size_t)255;
    float* hP   = (float*)(ws + off); off += (size_t)N_TOT * GNN_DIM * 4;
    __hip_bfloat16* hPb = (__hip_bfloat16*)(ws + off); off += (size_t)N_TOT * GNN_DIM * 2;
    __hip_bfloat16* mb  = (__hip_bfloat16*)(ws + off); off += (size_t)N_EDGES * GNN_DIM * 2;
    __hip_bfloat16* Xb0 = (__hip_bfloat16*)(ws + off); off += (size_t)N_TOT * IN_DIM * 2;
    __hip_bfloat16* Wt0 = (__hip_bfloat16*)(ws + off); off += (size_t)GNN_DIM * IN_DIM * 2;
    __hip_bfloat16* Wt1 = (__hip_bfloat16*)(ws + off); off += (size_t)GNN_DIM * GNN_DIM * 2;
    float* expL = (float*)(ws + off); off += (size_t)N_TOT * 12 * 4;
    float* sdst = (float*)(ws + off); off += (size_t)N_TOT * HEADS * 4;
    float* sedg = (float*)(ws + off); off += (size_t)N_EDGES * HEADS * 4;
    int* outrow = (int*)(ws + off); off += N_TILES * 4;
    __hip_bfloat16* hXb = Xb0;               // alias (Xb0 dead after layer-0 phaseA)

    // ----- fused prep -----
    prep1<<<9001, 256, 0, stream>>>(Hmat, HTb, HNb, W0, Wt0, W1, Wt1,
                                    x_nodes, readout, Xb0, ro_ids, outrow);

    // ----- layer 0 -----
    phaseA_mfma<<<N_TOT / 16, 256, 0, stream>>>(Xb0, Wt0, IN_DIM, IN_DIM + 8,
                                      node_emb, node_type,
                                      a_src, a_dst, edge_bias,
                                      hP, hPb, expL, sdst);
    phaseC_fused<<<N_EDGES, 512, 0, stream>>>(HTb, edge_type, expL, hPb,
                                              a_edge, mb, sedg);
    phaseE<<<N_TOT, 256, 0, stream>>>(HNb, sdst, sedg, mb, hP, hXb);

    // ----- layer 1 -----
    phaseA_mfma<<<N_TOT / 16, 256, 0, stream>>>(hXb, Wt1, GNN_DIM, GNN_DIM + 8,
                                      node_emb + 4 * GNN_DIM, node_type,
                                      a_src + HEADS * DH, a_dst + HEADS * DH,
                                      edge_bias + 12,
                                      hP, hPb, expL, sdst);
    phaseC_fused<<<N_EDGES, 512, 0, stream>>>(HTb, edge_type, expL, hPb,
                                              a_edge + HEADS * DH, mb, sedg);
    phaseE_last<<<N_TOT, 256, 0, stream>>>(HNb, sdst, sedg, mb, hP,
                                           node_g, node_b, bag_g, bag_b, outrow,
                                           (float*)d_out);
}